// Round 13
// baseline (2133.508 us; speedup 1.0000x reference)
//
#include <hip/hip_runtime.h>
#include <hip/hip_fp16.h>

#define EDIM 256
#define HDIM 512
#define CDIM 50257
#define NT_FC 197                 // ceil(50257 / 256) n-tiles
#define NJOBS (NT_FC * 4)         // x 4 m-tiles

using half2_t = __attribute__((ext_vector_type(2))) _Float16;
using half8_t = __attribute__((ext_vector_type(8))) _Float16;
using float4_t = __attribute__((ext_vector_type(4))) float;

__device__ __forceinline__ float dot2(uint32_t w, uint32_t h, float acc) {
    return __builtin_amdgcn_fdot2(__builtin_bit_cast(half2_t, w),
                                  __builtin_bit_cast(half2_t, h), acc, false);
}

// tanh(x) = 1 - 2/(exp2(2x*log2e)+1)
__device__ __forceinline__ float fast_tanh(float x) {
    float e = __builtin_amdgcn_exp2f(x * 2.8853900817779268f);
    return 1.f - 2.f * __builtin_amdgcn_rcpf(e + 1.f);
}

// ---------------------------------------------------------------------------
// 2-CU cooperative scan. Block half hb2 owns rows [hb2*256, +256).
// Thread t: rg = t>>4 owns rows hb2*256 + rg*8 + [0,8), c = t&15 owns
// k-slice [c*32, +32). Weights: 32 uint4 = 128 words, FULLY register
// resident (no LDS/global weight streaming at all — the R6 kernel's DS
// bottleneck is gone; each CU only holds 256 KB of weights now).
// Per step: read full h (512 f16) from the parity buffer hx[t&1] (partner
// half arrives via the shared intra-XCD L2 — blocks 0 and 8 land on XCD 0),
// 128 dot2, 7 paired DPP/swizzle folds + 1 xor8 self-add, tanh, store own
// 256 h to hx[(t+1)&1], then release-store my flag = t+1; partner spins
// relaxed + threadfence (R11/R12-validated protocol; correct cross-XCD too,
// just slower). Flag lag guarantees the 2-deep parity buffers are race-free.
// ---------------------------------------------------------------------------
__device__ __forceinline__ void scan2_body(
    const uint4* __restrict__ wp4,   // my half's [32][512] uint4 granules
    const float* __restrict__ z,     // [nsteps][512] f32
    _Float16* __restrict__ hxA, _Float16* __restrict__ hxB,  // parity bufs
    int* myflag, int* pflag,
    _Float16* __restrict__ hs_out,   // null or [nsteps][512]
    _Float16* __restrict__ hfin_out, // null or [512]
    int hb2, int nsteps) {
    const int tid = threadIdx.x;
    const int c = tid & 15, rg = tid >> 4;
    const int grow = hb2 * 256 + rg * 8 + (c & 7);

    uint4 wreg4[32];
#pragma unroll
    for (int g = 0; g < 32; ++g) wreg4[g] = wp4[g * 512 + tid];

    for (int t = 0; t < nsteps; ++t) {
        if (tid == 0) {
            while (__hip_atomic_load(pflag, __ATOMIC_RELAXED,
                                     __HIP_MEMORY_SCOPE_AGENT) < t) {}
            __threadfence();               // invalidate L1 before fresh h read
        }
        __syncthreads();
        const _Float16* hcur = (t & 1) ? hxB : hxA;
        _Float16*       hnxt = (t & 1) ? hxA : hxB;
        float zv = z[t * HDIM + grow];     // issued early, consumed late
        uint4 hg0 = ((const uint4*)hcur)[c * 4 + 0];
        uint4 hg1 = ((const uint4*)hcur)[c * 4 + 1];
        uint4 hg2 = ((const uint4*)hcur)[c * 4 + 2];
        uint4 hg3 = ((const uint4*)hcur)[c * 4 + 3];

        float acc[8] = {0.f, 0.f, 0.f, 0.f, 0.f, 0.f, 0.f, 0.f};
#define MAC_I(I, HG)                                                          \
        _Pragma("unroll")                                                     \
        for (int jr = 0; jr < 8; ++jr) {                                      \
            acc[jr] = dot2(wreg4[jr * 4 + I].x, HG.x, acc[jr]);               \
            acc[jr] = dot2(wreg4[jr * 4 + I].y, HG.y, acc[jr]);               \
            acc[jr] = dot2(wreg4[jr * 4 + I].z, HG.z, acc[jr]);               \
            acc[jr] = dot2(wreg4[jr * 4 + I].w, HG.w, acc[jr]);               \
        }
        MAC_I(0, hg0) MAC_I(1, hg1) MAC_I(2, hg2) MAC_I(3, hg3)
#undef MAC_I
        // fold 8 accs over c bits 0..2 (row select), then xor8 self-add.
        float s, keep;
#define FOLD_DPP(aL, aH, bit, ctrl, dst)                                      \
        s = (c & bit) ? (aL) : (aH);                                          \
        s = __builtin_bit_cast(float, __builtin_amdgcn_mov_dpp(               \
                __builtin_bit_cast(int, s), ctrl, 0xF, 0xF, true));           \
        keep = (c & bit) ? (aH) : (aL);                                       \
        dst = keep + s;
        float f0, f1, f2, f3, g0, g1, e, v;
        FOLD_DPP(acc[0], acc[1], 1, 0xB1, f0)   // xor1
        FOLD_DPP(acc[2], acc[3], 1, 0xB1, f1)
        FOLD_DPP(acc[4], acc[5], 1, 0xB1, f2)
        FOLD_DPP(acc[6], acc[7], 1, 0xB1, f3)
        FOLD_DPP(f0, f1, 2, 0x4E, g0)           // xor2
        FOLD_DPP(f2, f3, 2, 0x4E, g1)
        s = (c & 4) ? g0 : g1;                  // xor4 via ds_swizzle
        s = __builtin_bit_cast(float, __builtin_amdgcn_ds_swizzle(
                __builtin_bit_cast(int, s), 0x101F));
        keep = (c & 4) ? g1 : g0;
        e = keep + s;
        s = __builtin_bit_cast(float, __builtin_amdgcn_mov_dpp(   // xor8 add
                __builtin_bit_cast(int, e), 0x128, 0xF, 0xF, true));
        v = e + s;
#undef FOLD_DPP
        float hnew = fast_tanh(v + zv);
        _Float16 h16v = (_Float16)hnew;
        if (c < 8) {
            hnxt[grow] = h16v;
            if (hs_out) hs_out[t * HDIM + grow] = h16v;
            if (hfin_out && t == nsteps - 1) hfin_out[grow] = h16v;
        }
        __syncthreads();                   // drains vmcnt: stores complete
        if (tid == 0)
            __hip_atomic_store(myflag, t + 1, __ATOMIC_RELEASE,
                               __HIP_MEMORY_SCOPE_AGENT);
    }
}

// pack whh -> granules for scan2: flat G in [0,32768):
// hb2 = G>>14, g = (G>>9)&31, tt = G&511; jr = g>>2, i = g&3;
// row = hb2*256 + (tt>>4)*8 + jr; k0 = (tt&15)*32 + i*8.  dst[G] = granule.
__device__ __forceinline__ void pack_one(const float* __restrict__ whh,
                                         _Float16* __restrict__ wp, int G) {
    int hb2 = G >> 14, g = (G >> 9) & 31, tt = G & 511;
    int row = hb2 * 256 + ((tt >> 4) << 3) + (g >> 2);
    int k0 = ((tt & 15) << 5) + ((g & 3) << 3);
    const float* src = whh + row * HDIM + k0;
    uint32_t d[4];
#pragma unroll
    for (int q = 0; q < 4; ++q) {
        half2_t p;
        p[0] = (_Float16)src[2 * q];
        p[1] = (_Float16)src[2 * q + 1];
        d[q] = __builtin_bit_cast(uint32_t, p);
    }
    ((uint4*)wp)[G] = make_uint4(d[0], d[1], d[2], d[3]);
}

// ---------------------------------------------------------------------------
// prep_a: b==0 init (flags, hx_enc[0]=0); b in [1,65) pack enc; b in
// [65,577) zker encoder t = b-65.
// ---------------------------------------------------------------------------
__global__ void __launch_bounds__(512) prep_a(
    const float* __restrict__ enc_whh, _Float16* __restrict__ wpe,
    const int* __restrict__ in_ids, const float* __restrict__ emb,
    const float* __restrict__ enc_wih, const float* __restrict__ enc_bih,
    const float* __restrict__ enc_bhh, float* __restrict__ z,
    int* __restrict__ flags, _Float16* __restrict__ hx_enc) {
    __shared__ float x[EDIM];
    int b = blockIdx.x, tid = threadIdx.x;
    if (b == 0) {
        if (tid < 128)
            __hip_atomic_store(flags + tid, 0, __ATOMIC_RELAXED,
                               __HIP_MEMORY_SCOPE_AGENT);
        hx_enc[tid] = (_Float16)0.f;       // hx_enc parity-A = h0 = zeros
        return;
    }
    if (b < 65) {
        pack_one(enc_whh, wpe, (b - 1) * 512 + tid);
        return;
    }
    int t = b - 65;                        // 0..511
    int id = in_ids[t];
    if (tid < EDIM) x[tid] = emb[(long)id * EDIM + tid];
    __syncthreads();
    const float4* w4 = (const float4*)(enc_wih + tid * EDIM);
    float acc = 0.f;
#pragma unroll 8
    for (int k4 = 0; k4 < 64; ++k4) {
        float4 wv = w4[k4];
        acc += wv.x * x[k4 * 4 + 0] + wv.y * x[k4 * 4 + 1] +
               wv.z * x[k4 * 4 + 2] + wv.w * x[k4 * 4 + 3];
    }
    z[t * HDIM + tid] = acc + enc_bih[tid] + enc_bhh[tid];
}

// ---------------------------------------------------------------------------
// enc_fused: blocks 0 & 8 = encoder scan halves (flags encf0/encf1, final h
// written straight into hx_dec parity-A). Other blocks: pack dec (64),
// zker decoder (512), cvt fc_w (rest). 130KB LDS forces 1 block/CU so no
// prep block ever co-resides with a scan block's CU.
// ---------------------------------------------------------------------------
__global__ void __launch_bounds__(512, 2) enc_fused(
    const _Float16* __restrict__ wpe, const float* __restrict__ z,
    int* __restrict__ flags,
    _Float16* __restrict__ hx_enc, _Float16* __restrict__ hx_dec,
    const float* __restrict__ dec_whh, _Float16* __restrict__ wpd,
    const int* __restrict__ out_ids, const float* __restrict__ emb,
    const float* __restrict__ dec_wih, const float* __restrict__ dec_bih,
    const float* __restrict__ dec_bhh, float* __restrict__ zf,
    const float* __restrict__ fc_w, _Float16* __restrict__ fcw16, long fcw_n) {
    __shared__ uint4 ldsbig[16 * 512];     // occupancy force + zker staging
    int b = blockIdx.x, tid = threadIdx.x;
    if (tid == 511) *(volatile unsigned int*)&ldsbig[0] = 0u;
    if (b == 0 || b == 8) {
        int hb2 = (b == 8) ? 1 : 0;
        scan2_body((const uint4*)wpe + hb2 * 32 * 512, z,
                   hx_enc, hx_enc + 512,
                   flags + hb2 * 32, flags + (1 - hb2) * 32,
                   nullptr, hx_dec, hb2, 512);
        return;
    }
    int jb = (b < 8) ? b - 1 : b - 2;
    if (jb < 64) {
        pack_one(dec_whh, wpd, jb * 512 + tid);
    } else if (jb < 576) {
        int t = 512 + (jb - 64);
        float* x = (float*)ldsbig;
        int id = (t == 512) ? 1 : out_ids[t - 513];
        if (tid < EDIM) x[tid] = emb[(long)id * EDIM + tid];
        __syncthreads();
        const float4* w4 = (const float4*)(dec_wih + tid * EDIM);
        float acc = 0.f;
#pragma unroll 8
        for (int k4 = 0; k4 < 64; ++k4) {
            float4 wv = w4[k4];
            acc += wv.x * x[k4 * 4 + 0] + wv.y * x[k4 * 4 + 1] +
                   wv.z * x[k4 * 4 + 2] + wv.w * x[k4 * 4 + 3];
        }
        zf[t * HDIM + tid] = acc + dec_bih[tid] + dec_bhh[tid];
    } else {
        long i = ((long)(jb - 576) * 512 + tid) * 8;
        if (i + 8 <= fcw_n) {
            const float4* s4 = (const float4*)(fc_w + i);
            float4 a = s4[0], bb = s4[1];
            half8_t o;
            o[0] = (_Float16)a.x;  o[1] = (_Float16)a.y;
            o[2] = (_Float16)a.z;  o[3] = (_Float16)a.w;
            o[4] = (_Float16)bb.x; o[5] = (_Float16)bb.y;
            o[6] = (_Float16)bb.z; o[7] = (_Float16)bb.w;
            *(half8_t*)(fcw16 + i) = o;
        }
    }
}

// ---------------------------------------------------------------------------
// dec_fc: blocks 0 & 8 = decoder scan halves (flags decf0/decf1; flags ARE
// the progress counters for FC). FC consumers = blocks with (b&7)!=0
// (XCD-0 blocks idle: isolates the scan XCD's L2 from FC traffic and the
// per-step wbl2 from FC dirty lines). Dense consumer index di = b-(b>>3)-1,
// stride 224. Each job: wait both flags >= (mj+1)*128 (relaxed poll),
// one threadfence, then 128m x 256n MFMA tile.
// ---------------------------------------------------------------------------
__global__ void __launch_bounds__(512, 2) dec_fc(
    const _Float16* __restrict__ wpd, const float* __restrict__ zdec,
    _Float16* __restrict__ hx_dec, _Float16* __restrict__ h16,
    int* __restrict__ flags,
    const _Float16* __restrict__ Bw16, const float* __restrict__ Bw32,
    int use16, const float* __restrict__ bias, float* __restrict__ out) {
    __shared__ uint4 ldsbig[16 * 512];     // occupancy force (1 block/CU)
    int b = blockIdx.x, tid = threadIdx.x;
    if (tid == 511) *(volatile unsigned int*)&ldsbig[0] = 0u;
    int* decf0 = flags + 64;
    int* decf1 = flags + 96;
    if (b == 0 || b == 8) {
        int hb2 = (b == 8) ? 1 : 0;
        scan2_body((const uint4*)wpd + hb2 * 32 * 512, zdec,
                   hx_dec, hx_dec + 512,
                   (hb2 ? decf1 : decf0), (hb2 ? decf0 : decf1),
                   h16, nullptr, hb2, 512);
        return;
    }
    if ((b & 7) == 0) return;              // keep XCD 0 clear of FC traffic
    int di = b - (b >> 3) - 1;             // dense 0..223
    int w = tid >> 6, l = tid & 63;
    int wm = (w >> 2) * 64, wn = (w & 3) * 64;
    int lr = l & 15, lk = (l >> 4) * 8;
    for (int j = di; j < NJOBS; j += 224) {
        int mj = j / NT_FC, nj = j - mj * NT_FC;
        if (tid == 0) {
            int need = (mj + 1) * 128;
            while (__hip_atomic_load(decf0, __ATOMIC_RELAXED,
                                     __HIP_MEMORY_SCOPE_AGENT) < need ||
                   __hip_atomic_load(decf1, __ATOMIC_RELAXED,
                                     __HIP_MEMORY_SCOPE_AGENT) < need)
                __builtin_amdgcn_s_sleep(64);
            __threadfence();   // one-time invalidate before reading h16
        }
        __syncthreads();
        int m0 = mj * 128, n0 = nj * 256;
        float4_t acc[4][4];
#pragma unroll
        for (int fm = 0; fm < 4; ++fm)
#pragma unroll
            for (int fn = 0; fn < 4; ++fn)
                acc[fm][fn] = (float4_t){0.f, 0.f, 0.f, 0.f};
        for (int ks = 0; ks < 512; ks += 32) {
            half8_t a[4], bf[4];
#pragma unroll
            for (int f = 0; f < 4; ++f) {
                int m = m0 + wm + f * 16 + lr;
                a[f] = *(const half8_t*)(h16 + (long)m * 512 + ks + lk);
                int n = n0 + wn + f * 16 + lr;
                if (n < CDIM) {
                    if (use16) {
                        bf[f] = *(const half8_t*)(Bw16 + (long)n * 512 + ks + lk);
                    } else {
                        const float4* bp4 =
                            (const float4*)(Bw32 + (long)n * 512 + ks + lk);
                        float4 x0 = bp4[0], x1 = bp4[1];
                        half8_t bb;
                        bb[0] = (_Float16)x0.x; bb[1] = (_Float16)x0.y;
                        bb[2] = (_Float16)x0.z; bb[3] = (_Float16)x0.w;
                        bb[4] = (_Float16)x1.x; bb[5] = (_Float16)x1.y;
                        bb[6] = (_Float16)x1.z; bb[7] = (_Float16)x1.w;
                        bf[f] = bb;
                    }
                } else {
#pragma unroll
                    for (int e = 0; e < 8; ++e) bf[f][e] = (_Float16)0.f;
                }
            }
#pragma unroll
            for (int fm = 0; fm < 4; ++fm)
#pragma unroll
                for (int fn = 0; fn < 4; ++fn)
                    acc[fm][fn] = __builtin_amdgcn_mfma_f32_16x16x32_f16(
                        a[fm], bf[fn], acc[fm][fn], 0, 0, 0);
        }
#pragma unroll
        for (int fn = 0; fn < 4; ++fn) {
            int n = n0 + wn + fn * 16 + lr;
            if (n >= CDIM) continue;
            float bv = bias[n];
#pragma unroll
            for (int fm = 0; fm < 4; ++fm) {
#pragma unroll
                for (int q = 0; q < 4; ++q) {
                    int m = m0 + wm + fm * 16 + (l >> 4) * 4 + q;
                    out[(long)m * CDIM + n] = acc[fm][fn][q] + bv;
                }
            }
        }
    }
}

// ---------------------------------------------------------------------------
// Workspace layout:
//   [0, 2MB)            z  f32 [1024][512]
//   [2MB, 2.5MB)        wp2_enc f16 (2 halves x 32 granules x 512 thr x 16B)
//   [2.5MB, 3MB)        wp2_dec f16
//   [3MB, 3.5MB)        h16 f16 [512][512]
//   [3.5MB, +512B)      flags int[128] (4 used, 128B apart)
//   [3.5MB+512, +2KB)   hx_enc f16 [2][512]
//   [3.5MB+2560, +2KB)  hx_dec f16 [2][512]
//   [4MB, 4MB+51.5MB)   fc_w16 (only if ws_size permits)
// ---------------------------------------------------------------------------
extern "C" void kernel_launch(void* const* d_in, const int* in_sizes, int n_in,
                              void* d_out, int out_size, void* d_ws, size_t ws_size,
                              hipStream_t stream) {
    const int* input_ids  = (const int*)d_in[1];
    const int* output_ids = (const int*)d_in[2];
    const float* emb      = (const float*)d_in[3];
    const float* enc_wih  = (const float*)d_in[4];
    const float* enc_whh  = (const float*)d_in[5];
    const float* enc_bih  = (const float*)d_in[6];
    const float* enc_bhh  = (const float*)d_in[7];
    const float* dec_wih  = (const float*)d_in[8];
    const float* dec_whh  = (const float*)d_in[9];
    const float* dec_bih  = (const float*)d_in[10];
    const float* dec_bhh  = (const float*)d_in[11];
    const float* fc_w     = (const float*)d_in[12];
    const float* fc_b     = (const float*)d_in[13];
    float* out = (float*)d_out;

    char* ws = (char*)d_ws;
    float* z        = (float*)ws;                                  // 2 MB
    _Float16* wpe   = (_Float16*)(ws + (2u << 20));                // 512 KB
    _Float16* wpd   = (_Float16*)(ws + (2u << 20) + (512u << 10)); // 512 KB
    _Float16* h16   = (_Float16*)(ws + (3u << 20));                // 512 KB
    int* flags      = (int*)(ws + (3u << 20) + (512u << 10));      // 512 B
    _Float16* hx_enc = (_Float16*)(ws + (3u << 20) + (512u << 10) + 512);
    _Float16* hx_dec = (_Float16*)(ws + (3u << 20) + (512u << 10) + 2560);
    _Float16* fcw16 = (_Float16*)(ws + (4u << 20));                // 51.5 MB

    const long fcw_n = (long)CDIM * HDIM;
    bool use_f16_fc = ws_size >= (size_t)(4u << 20) + (size_t)fcw_n * 2;
    int nb_cvt = use_f16_fc ? (int)((fcw_n / 8 + 511) / 512) : 0;

    // 1: init flags/hx + pack enc + encoder z
    prep_a<<<577, 512, 0, stream>>>(enc_whh, wpe, input_ids, emb,
                                    enc_wih, enc_bih, enc_bhh, z,
                                    flags, hx_enc);
    // 2: encoder 2-CU scan (blocks 0,8) || pack dec + decoder z + fc_w cvt
    enc_fused<<<578 + nb_cvt, 512, 0, stream>>>(
        wpe, z, flags, hx_enc, hx_dec,
        dec_whh, wpd, output_ids, emb,
        dec_wih, dec_bih, dec_bhh, z, fc_w, fcw16, fcw_n);
    // 3: decoder 2-CU scan (blocks 0,8; flags = FC progress) || FC consumers
    dec_fc<<<256, 512, 0, stream>>>(wpd, z + 512 * HDIM, hx_dec, h16, flags,
                                    fcw16, fc_w, use_f16_fc ? 1 : 0,
                                    fc_b, out);
}

// Round 14
// 2115.475 us; speedup vs baseline: 1.0085x; 1.0085x over previous
//
#include <hip/hip_runtime.h>
#include <hip/hip_fp16.h>

#define EDIM 256
#define HDIM 512
#define CDIM 50257
#define NT_FC 197                 // ceil(50257 / 256) n-tiles
#define NJOBS (NT_FC * 4)         // x 4 m-tiles

using half2_t = __attribute__((ext_vector_type(2))) _Float16;
using half8_t = __attribute__((ext_vector_type(8))) _Float16;
using float4_t = __attribute__((ext_vector_type(4))) float;

__device__ __forceinline__ float dot2(uint32_t w, uint32_t h, float acc) {
    return __builtin_amdgcn_fdot2(__builtin_bit_cast(half2_t, w),
                                  __builtin_bit_cast(half2_t, h), acc, false);
}

// tanh(x) = 1 - 2/(exp2(2x*log2e)+1)
__device__ __forceinline__ float fast_tanh(float x) {
    float e = __builtin_amdgcn_exp2f(x * 2.8853900817779268f);
    return 1.f - 2.f * __builtin_amdgcn_rcpf(e + 1.f);
}

// ---------------------------------------------------------------------------
// 2-CU cooperative scan. Block half hb2 owns rows [hb2*256, +256).
// Thread t: rg = t>>4 owns rows hb2*256 + rg*8 + [0,8), c = t&15 owns
// k-slice [c*32, +32). Weights: 32 uint4 = 128 words, FULLY register
// resident (no LDS/global weight streaming at all — the R6 kernel's DS
// bottleneck is gone; each CU only holds 256 KB of weights now).
// Per step: read full h (512 f16) from the parity buffer hx[t&1] (partner
// half arrives via the shared intra-XCD L2 — blocks 0 and 8 land on XCD 0),
// 128 dot2, 7 paired DPP/swizzle folds + 1 xor8 self-add, tanh, store own
// 256 h to hx[(t+1)&1], then release-store my flag = t+1; partner spins
// relaxed + threadfence (R11/R12-validated protocol; correct cross-XCD too,
// just slower). Flag lag guarantees the 2-deep parity buffers are race-free.
// ---------------------------------------------------------------------------
__device__ __forceinline__ void scan2_body(
    const uint4* __restrict__ wp4,   // my half's [32][512] uint4 granules
    const float* __restrict__ z,     // [nsteps][512] f32
    _Float16* __restrict__ hxA, _Float16* __restrict__ hxB,  // parity bufs
    int* myflag, int* pflag,
    _Float16* __restrict__ hs_out,   // null or [nsteps][512]
    _Float16* __restrict__ hfin_out, // null or [512]
    int hb2, int nsteps) {
    const int tid = threadIdx.x;
    const int c = tid & 15, rg = tid >> 4;
    const int grow = hb2 * 256 + rg * 8 + (c & 7);

    uint4 wreg4[32];
#pragma unroll
    for (int g = 0; g < 32; ++g) wreg4[g] = wp4[g * 512 + tid];

    for (int t = 0; t < nsteps; ++t) {
        if (tid == 0) {
            while (__hip_atomic_load(pflag, __ATOMIC_RELAXED,
                                     __HIP_MEMORY_SCOPE_AGENT) < t) {}
            __threadfence();               // invalidate L1 before fresh h read
        }
        __syncthreads();
        const _Float16* hcur = (t & 1) ? hxB : hxA;
        _Float16*       hnxt = (t & 1) ? hxA : hxB;
        float zv = z[t * HDIM + grow];     // issued early, consumed late
        uint4 hg0 = ((const uint4*)hcur)[c * 4 + 0];
        uint4 hg1 = ((const uint4*)hcur)[c * 4 + 1];
        uint4 hg2 = ((const uint4*)hcur)[c * 4 + 2];
        uint4 hg3 = ((const uint4*)hcur)[c * 4 + 3];

        float acc[8] = {0.f, 0.f, 0.f, 0.f, 0.f, 0.f, 0.f, 0.f};
#define MAC_I(I, HG)                                                          \
        _Pragma("unroll")                                                     \
        for (int jr = 0; jr < 8; ++jr) {                                      \
            acc[jr] = dot2(wreg4[jr * 4 + I].x, HG.x, acc[jr]);               \
            acc[jr] = dot2(wreg4[jr * 4 + I].y, HG.y, acc[jr]);               \
            acc[jr] = dot2(wreg4[jr * 4 + I].z, HG.z, acc[jr]);               \
            acc[jr] = dot2(wreg4[jr * 4 + I].w, HG.w, acc[jr]);               \
        }
        MAC_I(0, hg0) MAC_I(1, hg1) MAC_I(2, hg2) MAC_I(3, hg3)
#undef MAC_I
        // fold 8 accs over c bits 0..2 (row select), then xor8 self-add.
        float s, keep;
#define FOLD_DPP(aL, aH, bit, ctrl, dst)                                      \
        s = (c & bit) ? (aL) : (aH);                                          \
        s = __builtin_bit_cast(float, __builtin_amdgcn_mov_dpp(               \
                __builtin_bit_cast(int, s), ctrl, 0xF, 0xF, true));           \
        keep = (c & bit) ? (aH) : (aL);                                       \
        dst = keep + s;
        float f0, f1, f2, f3, g0, g1, e, v;
        FOLD_DPP(acc[0], acc[1], 1, 0xB1, f0)   // xor1
        FOLD_DPP(acc[2], acc[3], 1, 0xB1, f1)
        FOLD_DPP(acc[4], acc[5], 1, 0xB1, f2)
        FOLD_DPP(acc[6], acc[7], 1, 0xB1, f3)
        FOLD_DPP(f0, f1, 2, 0x4E, g0)           // xor2
        FOLD_DPP(f2, f3, 2, 0x4E, g1)
        s = (c & 4) ? g0 : g1;                  // xor4 via ds_swizzle
        s = __builtin_bit_cast(float, __builtin_amdgcn_ds_swizzle(
                __builtin_bit_cast(int, s), 0x101F));
        keep = (c & 4) ? g1 : g0;
        e = keep + s;
        s = __builtin_bit_cast(float, __builtin_amdgcn_mov_dpp(   // xor8 add
                __builtin_bit_cast(int, e), 0x128, 0xF, 0xF, true));
        v = e + s;
#undef FOLD_DPP
        float hnew = fast_tanh(v + zv);
        _Float16 h16v = (_Float16)hnew;
        if (c < 8) {
            hnxt[grow] = h16v;
            if (hs_out) hs_out[t * HDIM + grow] = h16v;
            if (hfin_out && t == nsteps - 1) hfin_out[grow] = h16v;
        }
        __syncthreads();                   // drains vmcnt: stores complete
        if (tid == 0)
            __hip_atomic_store(myflag, t + 1, __ATOMIC_RELEASE,
                               __HIP_MEMORY_SCOPE_AGENT);
    }
}

// pack whh -> granules for scan2: flat G in [0,32768):
// hb2 = G>>14, g = (G>>9)&31, tt = G&511; jr = g>>2, i = g&3;
// row = hb2*256 + (tt>>4)*8 + jr; k0 = (tt&15)*32 + i*8.  dst[G] = granule.
__device__ __forceinline__ void pack_one(const float* __restrict__ whh,
                                         _Float16* __restrict__ wp, int G) {
    int hb2 = G >> 14, g = (G >> 9) & 31, tt = G & 511;
    int row = hb2 * 256 + ((tt >> 4) << 3) + (g >> 2);
    int k0 = ((tt & 15) << 5) + ((g & 3) << 3);
    const float* src = whh + row * HDIM + k0;
    uint32_t d[4];
#pragma unroll
    for (int q = 0; q < 4; ++q) {
        half2_t p;
        p[0] = (_Float16)src[2 * q];
        p[1] = (_Float16)src[2 * q + 1];
        d[q] = __builtin_bit_cast(uint32_t, p);
    }
    ((uint4*)wp)[G] = make_uint4(d[0], d[1], d[2], d[3]);
}

// ---------------------------------------------------------------------------
// prep_a: b==0 init (flags, hx_enc[0]=0); b in [1,65) pack enc; b in
// [65,577) zker encoder t = b-65.
// ---------------------------------------------------------------------------
__global__ void __launch_bounds__(512) prep_a(
    const float* __restrict__ enc_whh, _Float16* __restrict__ wpe,
    const int* __restrict__ in_ids, const float* __restrict__ emb,
    const float* __restrict__ enc_wih, const float* __restrict__ enc_bih,
    const float* __restrict__ enc_bhh, float* __restrict__ z,
    int* __restrict__ flags, _Float16* __restrict__ hx_enc) {
    __shared__ float x[EDIM];
    int b = blockIdx.x, tid = threadIdx.x;
    if (b == 0) {
        if (tid < 128)
            __hip_atomic_store(flags + tid, 0, __ATOMIC_RELAXED,
                               __HIP_MEMORY_SCOPE_AGENT);
        hx_enc[tid] = (_Float16)0.f;       // hx_enc parity-A = h0 = zeros
        return;
    }
    if (b < 65) {
        pack_one(enc_whh, wpe, (b - 1) * 512 + tid);
        return;
    }
    int t = b - 65;                        // 0..511
    int id = in_ids[t];
    if (tid < EDIM) x[tid] = emb[(long)id * EDIM + tid];
    __syncthreads();
    const float4* w4 = (const float4*)(enc_wih + tid * EDIM);
    float acc = 0.f;
#pragma unroll 8
    for (int k4 = 0; k4 < 64; ++k4) {
        float4 wv = w4[k4];
        acc += wv.x * x[k4 * 4 + 0] + wv.y * x[k4 * 4 + 1] +
               wv.z * x[k4 * 4 + 2] + wv.w * x[k4 * 4 + 3];
    }
    z[t * HDIM + tid] = acc + enc_bih[tid] + enc_bhh[tid];
}

// ---------------------------------------------------------------------------
// enc_fused: blocks 0 & 8 = encoder scan halves (flags encf0/encf1, final h
// written straight into hx_dec parity-A). Other blocks: pack dec (64),
// zker decoder (512), cvt fc_w (rest). 130KB LDS forces 1 block/CU so no
// prep block ever co-resides with a scan block's CU.
// ---------------------------------------------------------------------------
__global__ void __launch_bounds__(512, 2) enc_fused(
    const _Float16* __restrict__ wpe, const float* __restrict__ z,
    int* __restrict__ flags,
    _Float16* __restrict__ hx_enc, _Float16* __restrict__ hx_dec,
    const float* __restrict__ dec_whh, _Float16* __restrict__ wpd,
    const int* __restrict__ out_ids, const float* __restrict__ emb,
    const float* __restrict__ dec_wih, const float* __restrict__ dec_bih,
    const float* __restrict__ dec_bhh, float* __restrict__ zf,
    const float* __restrict__ fc_w, _Float16* __restrict__ fcw16, long fcw_n) {
    __shared__ uint4 ldsbig[16 * 512];     // occupancy force + zker staging
    int b = blockIdx.x, tid = threadIdx.x;
    if (tid == 511) *(volatile unsigned int*)&ldsbig[0] = 0u;
    if (b == 0 || b == 8) {
        int hb2 = (b == 8) ? 1 : 0;
        scan2_body((const uint4*)wpe + hb2 * 32 * 512, z,
                   hx_enc, hx_enc + 512,
                   flags + hb2 * 32, flags + (1 - hb2) * 32,
                   nullptr, hx_dec, hb2, 512);
        return;
    }
    int jb = (b < 8) ? b - 1 : b - 2;
    if (jb < 64) {
        pack_one(dec_whh, wpd, jb * 512 + tid);
    } else if (jb < 576) {
        int t = 512 + (jb - 64);
        float* x = (float*)ldsbig;
        int id = (t == 512) ? 1 : out_ids[t - 513];
        if (tid < EDIM) x[tid] = emb[(long)id * EDIM + tid];
        __syncthreads();
        const float4* w4 = (const float4*)(dec_wih + tid * EDIM);
        float acc = 0.f;
#pragma unroll 8
        for (int k4 = 0; k4 < 64; ++k4) {
            float4 wv = w4[k4];
            acc += wv.x * x[k4 * 4 + 0] + wv.y * x[k4 * 4 + 1] +
                   wv.z * x[k4 * 4 + 2] + wv.w * x[k4 * 4 + 3];
        }
        zf[t * HDIM + tid] = acc + dec_bih[tid] + dec_bhh[tid];
    } else {
        long i = ((long)(jb - 576) * 512 + tid) * 8;
        if (i + 8 <= fcw_n) {
            const float4* s4 = (const float4*)(fc_w + i);
            float4 a = s4[0], bb = s4[1];
            half8_t o;
            o[0] = (_Float16)a.x;  o[1] = (_Float16)a.y;
            o[2] = (_Float16)a.z;  o[3] = (_Float16)a.w;
            o[4] = (_Float16)bb.x; o[5] = (_Float16)bb.y;
            o[6] = (_Float16)bb.z; o[7] = (_Float16)bb.w;
            *(half8_t*)(fcw16 + i) = o;
        }
    }
}

// ---------------------------------------------------------------------------
// dec_fc: blocks 0 & 8 = decoder scan halves (flags decf0/decf1; flags ARE
// the progress counters for FC). FC consumers = blocks with (b&7)!=0
// (XCD-0 blocks idle: isolates the scan XCD's L2 from FC traffic and the
// per-step wbl2 from FC dirty lines). Dense consumer index di = b-(b>>3)-1,
// stride 224. Each job: wait both flags >= (mj+1)*128 (relaxed poll),
// one threadfence, then 128m x 256n MFMA tile.
// ---------------------------------------------------------------------------
__global__ void __launch_bounds__(512, 2) dec_fc(
    const _Float16* __restrict__ wpd, const float* __restrict__ zdec,
    _Float16* __restrict__ hx_dec, _Float16* __restrict__ h16,
    int* __restrict__ flags,
    const _Float16* __restrict__ Bw16, const float* __restrict__ Bw32,
    int use16, const float* __restrict__ bias, float* __restrict__ out) {
    __shared__ uint4 ldsbig[16 * 512];     // occupancy force (1 block/CU)
    int b = blockIdx.x, tid = threadIdx.x;
    if (tid == 511) *(volatile unsigned int*)&ldsbig[0] = 0u;
    int* decf0 = flags + 64;
    int* decf1 = flags + 96;
    if (b == 0 || b == 8) {
        int hb2 = (b == 8) ? 1 : 0;
        scan2_body((const uint4*)wpd + hb2 * 32 * 512, zdec,
                   hx_dec, hx_dec + 512,
                   (hb2 ? decf1 : decf0), (hb2 ? decf0 : decf1),
                   h16, nullptr, hb2, 512);
        return;
    }
    if ((b & 7) == 0) return;              // keep XCD 0 clear of FC traffic
    int di = b - (b >> 3) - 1;             // dense 0..223
    int w = tid >> 6, l = tid & 63;
    int wm = (w >> 2) * 64, wn = (w & 3) * 64;
    int lr = l & 15, lk = (l >> 4) * 8;
    for (int j = di; j < NJOBS; j += 224) {
        int mj = j / NT_FC, nj = j - mj * NT_FC;
        if (tid == 0) {
            int need = (mj + 1) * 128;
            while (__hip_atomic_load(decf0, __ATOMIC_RELAXED,
                                     __HIP_MEMORY_SCOPE_AGENT) < need ||
                   __hip_atomic_load(decf1, __ATOMIC_RELAXED,
                                     __HIP_MEMORY_SCOPE_AGENT) < need)
                __builtin_amdgcn_s_sleep(64);
            __threadfence();   // one-time invalidate before reading h16
        }
        __syncthreads();
        int m0 = mj * 128, n0 = nj * 256;
        float4_t acc[4][4];
#pragma unroll
        for (int fm = 0; fm < 4; ++fm)
#pragma unroll
            for (int fn = 0; fn < 4; ++fn)
                acc[fm][fn] = (float4_t){0.f, 0.f, 0.f, 0.f};
        for (int ks = 0; ks < 512; ks += 32) {
            half8_t a[4], bf[4];
#pragma unroll
            for (int f = 0; f < 4; ++f) {
                int m = m0 + wm + f * 16 + lr;
                a[f] = *(const half8_t*)(h16 + (long)m * 512 + ks + lk);
                int n = n0 + wn + f * 16 + lr;
                if (n < CDIM) {
                    if (use16) {
                        bf[f] = *(const half8_t*)(Bw16 + (long)n * 512 + ks + lk);
                    } else {
                        const float4* bp4 =
                            (const float4*)(Bw32 + (long)n * 512 + ks + lk);
                        float4 x0 = bp4[0], x1 = bp4[1];
                        half8_t bb;
                        bb[0] = (_Float16)x0.x; bb[1] = (_Float16)x0.y;
                        bb[2] = (_Float16)x0.z; bb[3] = (_Float16)x0.w;
                        bb[4] = (_Float16)x1.x; bb[5] = (_Float16)x1.y;
                        bb[6] = (_Float16)x1.z; bb[7] = (_Float16)x1.w;
                        bf[f] = bb;
                    }
                } else {
#pragma unroll
                    for (int e = 0; e < 8; ++e) bf[f][e] = (_Float16)0.f;
                }
            }
#pragma unroll
            for (int fm = 0; fm < 4; ++fm)
#pragma unroll
                for (int fn = 0; fn < 4; ++fn)
                    acc[fm][fn] = __builtin_amdgcn_mfma_f32_16x16x32_f16(
                        a[fm], bf[fn], acc[fm][fn], 0, 0, 0);
        }
#pragma unroll
        for (int fn = 0; fn < 4; ++fn) {
            int n = n0 + wn + fn * 16 + lr;
            if (n >= CDIM) continue;
            float bv = bias[n];
#pragma unroll
            for (int fm = 0; fm < 4; ++fm) {
#pragma unroll
                for (int q = 0; q < 4; ++q) {
                    int m = m0 + wm + fm * 16 + (l >> 4) * 4 + q;
                    out[(long)m * CDIM + n] = acc[fm][fn][q] + bv;
                }
            }
        }
    }
}

// ---------------------------------------------------------------------------
// Workspace layout:
//   [0, 2MB)            z  f32 [1024][512]
//   [2MB, 2.5MB)        wp2_enc f16 (2 halves x 32 granules x 512 thr x 16B)
//   [2.5MB, 3MB)        wp2_dec f16
//   [3MB, 3.5MB)        h16 f16 [512][512]
//   [3.5MB, +512B)      flags int[128] (4 used, 128B apart)
//   [3.5MB+512, +2KB)   hx_enc f16 [2][512]
//   [3.5MB+2560, +2KB)  hx_dec f16 [2][512]
//   [4MB, 4MB+51.5MB)   fc_w16 (only if ws_size permits)
// ---------------------------------------------------------------------------
extern "C" void kernel_launch(void* const* d_in, const int* in_sizes, int n_in,
                              void* d_out, int out_size, void* d_ws, size_t ws_size,
                              hipStream_t stream) {
    const int* input_ids  = (const int*)d_in[1];
    const int* output_ids = (const int*)d_in[2];
    const float* emb      = (const float*)d_in[3];
    const float* enc_wih  = (const float*)d_in[4];
    const float* enc_whh  = (const float*)d_in[5];
    const float* enc_bih  = (const float*)d_in[6];
    const float* enc_bhh  = (const float*)d_in[7];
    const float* dec_wih  = (const float*)d_in[8];
    const float* dec_whh  = (const float*)d_in[9];
    const float* dec_bih  = (const float*)d_in[10];
    const float* dec_bhh  = (const float*)d_in[11];
    const float* fc_w     = (const float*)d_in[12];
    const float* fc_b     = (const float*)d_in[13];
    float* out = (float*)d_out;

    char* ws = (char*)d_ws;
    float* z        = (float*)ws;                                  // 2 MB
    _Float16* wpe   = (_Float16*)(ws + (2u << 20));                // 512 KB
    _Float16* wpd   = (_Float16*)(ws + (2u << 20) + (512u << 10)); // 512 KB
    _Float16* h16   = (_Float16*)(ws + (3u << 20));                // 512 KB
    int* flags      = (int*)(ws + (3u << 20) + (512u << 10));      // 512 B
    _Float16* hx_enc = (_Float16*)(ws + (3u << 20) + (512u << 10) + 512);
    _Float16* hx_dec = (_Float16*)(ws + (3u << 20) + (512u << 10) + 2560);
    _Float16* fcw16 = (_Float16*)(ws + (4u << 20));                // 51.5 MB

    const long fcw_n = (long)CDIM * HDIM;
    bool use_f16_fc = ws_size >= (size_t)(4u << 20) + (size_t)fcw_n * 2;
    int nb_cvt = use_f16_fc ? (int)((fcw_n / 8 + 511) / 512) : 0;

    // 1: init flags/hx + pack enc + encoder z
    prep_a<<<577, 512, 0, stream>>>(enc_whh, wpe, input_ids, emb,
                                    enc_wih, enc_bih, enc_bhh, z,
                                    flags, hx_enc);
    // 2: encoder 2-CU scan (blocks 0,8) || pack dec + decoder z + fc_w cvt
    enc_fused<<<578 + nb_cvt, 512, 0, stream>>>(
        wpe, z, flags, hx_enc, hx_dec,
        dec_whh, wpd, output_ids, emb,
        dec_wih, dec_bih, dec_bhh, z, fc_w, fcw16, fcw_n);
    // 3: decoder 2-CU scan (blocks 0,8; flags = FC progress) || FC consumers
    dec_fc<<<256, 512, 0, stream>>>(wpd, z + 512 * HDIM, hx_dec, h16, flags,
                                    fcw16, fc_w, use_f16_fc ? 1 : 0,
                                    fc_b, out);
}

// Round 15
// 1366.127 us; speedup vs baseline: 1.5617x; 1.5485x over previous
//
#include <hip/hip_runtime.h>
#include <hip/hip_fp16.h>

#define EDIM 256
#define HDIM 512
#define CDIM 50257
#define NT_FC 197                 // ceil(50257 / 256) n-tiles
#define NJOBS (NT_FC * 4)         // x 4 m-tiles

using half2_t = __attribute__((ext_vector_type(2))) _Float16;
using half8_t = __attribute__((ext_vector_type(8))) _Float16;
using float4_t = __attribute__((ext_vector_type(4))) float;

__device__ __forceinline__ float dot2(uint32_t w, uint32_t h, float acc) {
    return __builtin_amdgcn_fdot2(__builtin_bit_cast(half2_t, w),
                                  __builtin_bit_cast(half2_t, h), acc, false);
}

// tanh(x) = 1 - 2/(exp2(2x*log2e)+1)
__device__ __forceinline__ float fast_tanh(float x) {
    float e = __builtin_amdgcn_exp2f(x * 2.8853900817779268f);
    return 1.f - 2.f * __builtin_amdgcn_rcpf(e + 1.f);
}

// ---------------------------------------------------------------------------
// Pack whh -> f16 granules [g=0..63][t=0..511][8 halves], XOR-SLOT layout
// (R8-validated): scan thread t: rg=t>>4 (16-row group), c=t&15 (32-wide k
// chunk); g = s*4 + i (slot s, granule i). Slot s on thread t holds ROW
// rg*16 + (s ^ c) — every fold level in the scan is then a single DPP/
// swizzle ADD (no cndmask selects), and after folding all 4 bits of c,
// lane c holds row rg*16+c == tid.
//   granule = whh[rg*16 + (s^c)][c*32 + i*8 + e], e = 0..7.
// slots 0..11 register-resident in scan; slots 12..15 streamed from LDS.
// ---------------------------------------------------------------------------
__device__ __forceinline__ void pack_one(const float* __restrict__ whh,
                                         _Float16* __restrict__ wp,
                                         int g, int t) {
    int row = ((t >> 4) << 4) + ((g >> 2) ^ (t & 15));
    int k0 = ((t & 15) << 5) + ((g & 3) << 3);
    const float* src = whh + row * HDIM + k0;
    uint32_t d[4];
#pragma unroll
    for (int q = 0; q < 4; ++q) {
        half2_t p;
        p[0] = (_Float16)src[2 * q];
        p[1] = (_Float16)src[2 * q + 1];
        d[q] = __builtin_bit_cast(uint32_t, p);
    }
    ((uint4*)wp)[g * 512 + t] = make_uint4(d[0], d[1], d[2], d[3]);
}

// ---------------------------------------------------------------------------
// Scan body: R6 dot2 engine (709-712 us validated) + R8 XOR-slot folds
// (numerics validated in R8). 1 workgroup, 512 threads (8 waves, 2/SIMD).
// Slots 0..11 register-resident (192 words), slots 12..15 streamed from
// LDS (128 KB). h f16 in LDS, double-buffered, [i][c] granule layout.
// Folds: 14 single DPP-adds (xor1 0xB1, xor2 0x4E, xor8 row_ror:8) + one
// ds_swizzle xor4 add. Fast inline tanh. One barrier per step.
// Optional progress publication every 128 steps (agent-scope release).
// ---------------------------------------------------------------------------
__device__ __forceinline__ void scan_body(
    const _Float16* __restrict__ wpack, const float* __restrict__ z,
    const _Float16* __restrict__ h_init, _Float16* __restrict__ hs_out,
    _Float16* __restrict__ hfin_out, int* prog, int nsteps,
    uint4* wlds, uint4* hbuf4) {
    const int tid = threadIdx.x;
    const int c = tid & 15;
    const int g_own = tid >> 3;
    const int hstore = 128 * (g_own & 3) + 8 * (g_own >> 2) + (tid & 7);

    const uint4* wp4 = (const uint4*)wpack;
    uint32_t wreg[192];                // slots 0..11 (4 granules each)
#pragma unroll
    for (int g = 0; g < 48; ++g) {
        uint4 v = wp4[g * 512 + tid];
        wreg[g * 4 + 0] = v.x; wreg[g * 4 + 1] = v.y;
        wreg[g * 4 + 2] = v.z; wreg[g * 4 + 3] = v.w;
    }
#pragma unroll
    for (int g = 48; g < 64; ++g) wlds[(g - 48) * 512 + tid] = wp4[g * 512 + tid];

    ((_Float16*)hbuf4)[hstore] = h_init ? h_init[tid] : (_Float16)0.f;
    __syncthreads();

    _Float16 hlast = (_Float16)0.f;
    int cur = 0;
    for (int t = 0; t < nsteps; ++t) {
        float zv = z[t * HDIM + tid];
        const uint4* hb = hbuf4 + cur * 64;
        float f[16];
#pragma unroll
        for (int r = 0; r < 16; ++r) f[r] = 0.f;
#pragma unroll
        for (int i = 0; i < 4; ++i) {
            uint4 hg = hb[i * 16 + c];
#pragma unroll
            for (int s = 0; s < 12; ++s) {
                f[s] = dot2(wreg[(s * 4 + i) * 4 + 0], hg.x, f[s]);
                f[s] = dot2(wreg[(s * 4 + i) * 4 + 1], hg.y, f[s]);
                f[s] = dot2(wreg[(s * 4 + i) * 4 + 2], hg.z, f[s]);
                f[s] = dot2(wreg[(s * 4 + i) * 4 + 3], hg.w, f[s]);
            }
#pragma unroll
            for (int js = 0; js < 4; ++js) {
                uint4 w = wlds[(js * 4 + i) * 512 + tid];
                f[12 + js] = dot2(w.x, hg.x, f[12 + js]);
                f[12 + js] = dot2(w.y, hg.y, f[12 + js]);
                f[12 + js] = dot2(w.z, hg.z, f[12 + js]);
                f[12 + js] = dot2(w.w, hg.w, f[12 + js]);
            }
        }
        // XOR-butterfly (R8-validated): slot s holds row (s^c); every fold
        // level is one add with a DPP/swizzle source.
#define DPPADD(DST, A, B, CTRL) {                                             \
        int _x = __builtin_amdgcn_mov_dpp(__builtin_bit_cast(int, (B)),       \
                                          CTRL, 0xF, 0xF, true);              \
        DST = (A) + __builtin_bit_cast(float, _x); }
        float t0, t2, t4, t6, t8, t10, t12, t14;
        DPPADD(t0,  f[0],  f[1],  0xB1)   // xor1: quad_perm(1,0,3,2)
        DPPADD(t2,  f[2],  f[3],  0xB1)
        DPPADD(t4,  f[4],  f[5],  0xB1)
        DPPADD(t6,  f[6],  f[7],  0xB1)
        DPPADD(t8,  f[8],  f[9],  0xB1)
        DPPADD(t10, f[10], f[11], 0xB1)
        DPPADD(t12, f[12], f[13], 0xB1)
        DPPADD(t14, f[14], f[15], 0xB1)
        float u0, u4, u8, u12;
        DPPADD(u0,  t0,  t2,  0x4E)       // xor2: quad_perm(2,3,0,1)
        DPPADD(u4,  t4,  t6,  0x4E)
        DPPADD(u8,  t8,  t10, 0x4E)
        DPPADD(u12, t12, t14, 0x4E)
        float v0, v4;
        DPPADD(v0, u0, u8,  0x128)        // xor8: row_ror:8 within 16 lanes
        DPPADD(v4, u4, u12, 0x128)
#undef DPPADD
        float sw = __builtin_bit_cast(float, __builtin_amdgcn_ds_swizzle(
                       __builtin_bit_cast(int, v4), 0x101F));  // xor4
        float vfin = v0 + sw;

        float hnew = fast_tanh(vfin + zv);
        _Float16 h16v = (_Float16)hnew;
        ((_Float16*)hbuf4)[(cur ^ 1) * 512 + hstore] = h16v;
        if (hs_out) hs_out[t * HDIM + tid] = h16v;
        hlast = h16v;
        __syncthreads();
        // barrier drained vmcnt(0): h16 rows <= t are in this XCD's L2.
        if (prog && (t & 127) == 127 && tid == 0) {
            __threadfence();
            __hip_atomic_store(prog, t + 1, __ATOMIC_RELEASE,
                               __HIP_MEMORY_SCOPE_AGENT);
        }
        cur ^= 1;
    }
    if (hfin_out) hfin_out[tid] = hlast;
}

// ---------------------------------------------------------------------------
// prep_a: zero progress flag + pack enc_whh + zker for encoder steps.
// blocks [0,128): pack; blocks [128,640): zker t in [0,512).
// ---------------------------------------------------------------------------
__global__ void __launch_bounds__(256) prep_a(
    const float* __restrict__ enc_whh, _Float16* __restrict__ wpe,
    const int* __restrict__ in_ids, const float* __restrict__ emb,
    const float* __restrict__ enc_wih, const float* __restrict__ enc_bih,
    const float* __restrict__ enc_bhh, float* __restrict__ z,
    int* __restrict__ prog) {
    __shared__ float x[EDIM];
    int b = blockIdx.x;
    if (b == 0 && threadIdx.x == 0)
        __hip_atomic_store(prog, 0, __ATOMIC_RELAXED, __HIP_MEMORY_SCOPE_AGENT);
    if (b < 128) {
        int idx = b * 256 + threadIdx.x;           // 0..32767
        pack_one(enc_whh, wpe, idx >> 9, idx & 511);
    } else {
        int t = b - 128;                           // 0..511
        int id = in_ids[t];
        x[threadIdx.x] = emb[(long)id * EDIM + threadIdx.x];
        __syncthreads();
#pragma unroll
        for (int rr = 0; rr < 2; ++rr) {
            int r = threadIdx.x + rr * 256;
            const float4* w4 = (const float4*)(enc_wih + r * EDIM);
            float acc = 0.f;
#pragma unroll 8
            for (int k4 = 0; k4 < 64; ++k4) {
                float4 wv = w4[k4];
                acc += wv.x * x[k4 * 4 + 0] + wv.y * x[k4 * 4 + 1] +
                       wv.z * x[k4 * 4 + 2] + wv.w * x[k4 * 4 + 3];
            }
            z[t * HDIM + r] = acc + enc_bih[r] + enc_bhh[r];
        }
    }
}

// ---------------------------------------------------------------------------
// enc_fused: block 0 = ENCODER scan (1 CU). All other blocks do the
// independent prep hidden under the scan: pack dec_whh (64 blocks),
// zker decoder steps (512 blocks), fc_w f32->f16 (rest).
// ---------------------------------------------------------------------------
__global__ void __launch_bounds__(512, 2) enc_fused(
    const _Float16* __restrict__ wpe, const float* __restrict__ z,
    _Float16* __restrict__ hn16,
    const float* __restrict__ dec_whh, _Float16* __restrict__ wpd,
    const int* __restrict__ out_ids, const float* __restrict__ emb,
    const float* __restrict__ dec_wih, const float* __restrict__ dec_bih,
    const float* __restrict__ dec_bhh, float* __restrict__ zf,
    const float* __restrict__ fc_w, _Float16* __restrict__ fcw16, long fcw_n) {
    __shared__ uint4 wlds[16 * 512];   // 128 KB (scan); reused as x[] by zker
    __shared__ uint4 hbuf4[2 * 64];
    int b = blockIdx.x, tid = threadIdx.x;
    if (b == 0) {
        scan_body(wpe, z, nullptr, nullptr, hn16, nullptr, 512, wlds, hbuf4);
    } else if (b < 65) {
        // pack dec_whh
        int idx = (b - 1) * 512 + tid;             // 0..32767
        pack_one(dec_whh, wpd, idx >> 9, idx & 511);
    } else if (b < 577) {
        // zker decoder: t in [512, 1024), 512 threads = 1 row each
        int t = 512 + (b - 65);
        float* x = (float*)wlds;
        int id = (t == 512) ? 1 : out_ids[t - 513];
        if (tid < EDIM) x[tid] = emb[(long)id * EDIM + tid];
        __syncthreads();
        const float4* w4 = (const float4*)(dec_wih + tid * EDIM);
        float acc = 0.f;
#pragma unroll 8
        for (int k4 = 0; k4 < 64; ++k4) {
            float4 wv = w4[k4];
            acc += wv.x * x[k4 * 4 + 0] + wv.y * x[k4 * 4 + 1] +
                   wv.z * x[k4 * 4 + 2] + wv.w * x[k4 * 4 + 3];
        }
        zf[t * HDIM + tid] = acc + dec_bih[tid] + dec_bhh[tid];
    } else {
        // cvt fc_w -> f16
        long i = ((long)(b - 577) * 512 + tid) * 8;
        if (i + 8 <= fcw_n) {
            const float4* s4 = (const float4*)(fc_w + i);
            float4 a = s4[0], bb = s4[1];
            half8_t o;
            o[0] = (_Float16)a.x;  o[1] = (_Float16)a.y;
            o[2] = (_Float16)a.z;  o[3] = (_Float16)a.w;
            o[4] = (_Float16)bb.x; o[5] = (_Float16)bb.y;
            o[6] = (_Float16)bb.z; o[7] = (_Float16)bb.w;
            *(half8_t*)(fcw16 + i) = o;
        }
    }
}

// ---------------------------------------------------------------------------
// dec_fc: block 0 = DECODER scan publishing progress every 128 steps.
// FC consumers = blocks with (b&7)!=0 only (XCD-0 blocks idle: keeps FC's
// L2/HBM traffic off the scan's XCD — R14-validated consumer structure).
// Dense consumer index di = b-(b>>3)-1, stride 224. Each job: RELAXED-poll
// the progress flag (no per-poll cache invalidate — R12-validated), one
// __threadfence after the wait, then a 128m x 256n MFMA tile.
// Deadlock-free: 256 blocks x 130KB LDS = 1 block/CU, all co-resident;
// block 0 never waits.
// ---------------------------------------------------------------------------
__global__ void __launch_bounds__(512, 2) dec_fc(
    const _Float16* __restrict__ wpd, const float* __restrict__ zdec,
    const _Float16* __restrict__ hn16, _Float16* __restrict__ h16,
    int* __restrict__ prog,
    const _Float16* __restrict__ Bw16, const float* __restrict__ Bw32,
    int use16, const float* __restrict__ bias, float* __restrict__ out) {
    __shared__ uint4 wlds[16 * 512];
    __shared__ uint4 hbuf4[2 * 64];
    int b = blockIdx.x, tid = threadIdx.x;
    if (b == 0) {
        scan_body(wpd, zdec, hn16, h16, nullptr, prog, 512, wlds, hbuf4);
        return;
    }
    if (tid == 511) *(volatile unsigned int*)&wlds[0] = 0u;  // keep LDS live
    if ((b & 7) == 0) return;              // keep XCD 0 clear of FC traffic
    int di = b - (b >> 3) - 1;             // dense 0..223
    int w = tid >> 6, l = tid & 63;
    int wm = (w >> 2) * 64, wn = (w & 3) * 64;
    int lr = l & 15, lk = (l >> 4) * 8;
    for (int j = di; j < NJOBS; j += 224) {
        int mj = j / NT_FC, nj = j - mj * NT_FC;
        if (tid == 0) {
            int need = (mj + 1) * 128;
            while (__hip_atomic_load(prog, __ATOMIC_RELAXED,
                                     __HIP_MEMORY_SCOPE_AGENT) < need)
                __builtin_amdgcn_s_sleep(64);
            __threadfence();   // one-time invalidate before reading h16
        }
        __syncthreads();
        int m0 = mj * 128, n0 = nj * 256;
        float4_t acc[4][4];
#pragma unroll
        for (int fm = 0; fm < 4; ++fm)
#pragma unroll
            for (int fn = 0; fn < 4; ++fn)
                acc[fm][fn] = (float4_t){0.f, 0.f, 0.f, 0.f};
        for (int ks = 0; ks < 512; ks += 32) {
            half8_t a[4], bf[4];
#pragma unroll
            for (int f = 0; f < 4; ++f) {
                int m = m0 + wm + f * 16 + lr;
                a[f] = *(const half8_t*)(h16 + (long)m * 512 + ks + lk);
                int n = n0 + wn + f * 16 + lr;
                if (n < CDIM) {
                    if (use16) {
                        bf[f] = *(const half8_t*)(Bw16 + (long)n * 512 + ks + lk);
                    } else {
                        const float4* bp4 =
                            (const float4*)(Bw32 + (long)n * 512 + ks + lk);
                        float4 x0 = bp4[0], x1 = bp4[1];
                        half8_t bb;
                        bb[0] = (_Float16)x0.x; bb[1] = (_Float16)x0.y;
                        bb[2] = (_Float16)x0.z; bb[3] = (_Float16)x0.w;
                        bb[4] = (_Float16)x1.x; bb[5] = (_Float16)x1.y;
                        bb[6] = (_Float16)x1.z; bb[7] = (_Float16)x1.w;
                        bf[f] = bb;
                    }
                } else {
#pragma unroll
                    for (int e = 0; e < 8; ++e) bf[f][e] = (_Float16)0.f;
                }
            }
#pragma unroll
            for (int fm = 0; fm < 4; ++fm)
#pragma unroll
                for (int fn = 0; fn < 4; ++fn)
                    acc[fm][fn] = __builtin_amdgcn_mfma_f32_16x16x32_f16(
                        a[fm], bf[fn], acc[fm][fn], 0, 0, 0);
        }
#pragma unroll
        for (int fn = 0; fn < 4; ++fn) {
            int n = n0 + wn + fn * 16 + lr;
            if (n >= CDIM) continue;
            float bv = bias[n];
#pragma unroll
            for (int fm = 0; fm < 4; ++fm) {
#pragma unroll
                for (int q = 0; q < 4; ++q) {
                    int m = m0 + wm + fm * 16 + (l >> 4) * 4 + q;
                    out[(long)m * CDIM + n] = acc[fm][fn][q] + bv;
                }
            }
        }
    }
}

// ---------------------------------------------------------------------------
// Workspace layout:
//   [0, 2MB)            z  f32 [1024][512]
//   [2MB, 2.5MB)        wpack_enc f16
//   [2.5MB, 3MB)        wpack_dec f16
//   [3MB, 3.5MB)        h16 f16 [512][512]
//   [3.5MB, +1KB)       hn16 f16 [512]
//   [3.5MB+1KB, +4B)    progress flag (int)
//   [4MB, 4MB+51.5MB)   fc_w16 (only if ws_size permits)
// ---------------------------------------------------------------------------
extern "C" void kernel_launch(void* const* d_in, const int* in_sizes, int n_in,
                              void* d_out, int out_size, void* d_ws, size_t ws_size,
                              hipStream_t stream) {
    const int* input_ids  = (const int*)d_in[1];
    const int* output_ids = (const int*)d_in[2];
    const float* emb      = (const float*)d_in[3];
    const float* enc_wih  = (const float*)d_in[4];
    const float* enc_whh  = (const float*)d_in[5];
    const float* enc_bih  = (const float*)d_in[6];
    const float* enc_bhh  = (const float*)d_in[7];
    const float* dec_wih  = (const float*)d_in[8];
    const float* dec_whh  = (const float*)d_in[9];
    const float* dec_bih  = (const float*)d_in[10];
    const float* dec_bhh  = (const float*)d_in[11];
    const float* fc_w     = (const float*)d_in[12];
    const float* fc_b     = (const float*)d_in[13];
    float* out = (float*)d_out;

    char* ws = (char*)d_ws;
    float* z        = (float*)ws;                                  // 2 MB
    _Float16* wpe   = (_Float16*)(ws + (2u << 20));                // 512 KB
    _Float16* wpd   = (_Float16*)(ws + (2u << 20) + (512u << 10)); // 512 KB
    _Float16* h16   = (_Float16*)(ws + (3u << 20));                // 512 KB
    _Float16* hn16  = (_Float16*)(ws + (3u << 20) + (512u << 10)); // 1 KB
    int* prog       = (int*)(ws + (3u << 20) + (513u << 10));      // 4 B
    _Float16* fcw16 = (_Float16*)(ws + (4u << 20));                // 51.5 MB

    const long fcw_n = (long)CDIM * HDIM;
    bool use_f16_fc = ws_size >= (size_t)(4u << 20) + (size_t)fcw_n * 2;
    int nb_cvt = use_f16_fc ? (int)((fcw_n / 8 + 511) / 512) : 0;

    // 1: zero progress + pack enc + encoder z
    prep_a<<<640, 256, 0, stream>>>(enc_whh, wpe, input_ids, emb,
                                    enc_wih, enc_bih, enc_bhh, z, prog);
    // 2: encoder scan (block 0) || pack dec + decoder z + fc_w cvt
    enc_fused<<<577 + nb_cvt, 512, 0, stream>>>(
        wpe, z, hn16, dec_whh, wpd, output_ids, emb,
        dec_wih, dec_bih, dec_bhh, z, fc_w, fcw16, fcw_n);
    // 3: decoder scan (block 0, publishes progress) || FC consumers
    dec_fc<<<256, 512, 0, stream>>>(wpd, z + 512 * HDIM, hn16, h16, prog,
                                    fcw16, fc_w, use_f16_fc ? 1 : 0,
                                    fc_b, out);
}